// Round 6
// baseline (2221.268 us; speedup 1.0000x reference)
//
#include <hip/hip_runtime.h>

// Round 5b (compile fix of r5): 64 rows/block, 1024 thr (16 waves = 2 row-
// groups x 8 col-groups). Wave = 32 rows x 64 permuted cols; the 4 n-tiles
// ARE the 4 gates of the same 16 units -> each lane holds i,f,g,o for its
// unit in acc[2][4]: no shfl/cndmask gate exchange. B-frags re-fetched from
// L2 every step (loop-invariant addresses, 2-deep kc pipeline) -> no
// persistent weight regs, no spills. h in LDS [2][64][128] bf16, XOR-swizzled
// (granule^row&7). obs and Wo read directly from global. c in f32 regs.
// Decoder pos-path folded into Whh_d -> pure LSTM, POS fire-and-forget,
// 1 barrier/step everywhere.

#define OBS_LEN 8
#define PRED_LEN 12
#define BATCH 131072
#define HID 128
#define NZ 512
#define KWT 128
#define ROWS 64

typedef float f32x4 __attribute__((ext_vector_type(4)));
typedef float f32x2 __attribute__((ext_vector_type(2)));
typedef unsigned short u16x8 __attribute__((ext_vector_type(8)));
typedef __bf16 bf16x8 __attribute__((ext_vector_type(8)));

#define K2F 1.4426950408889634f   // log2(e)

static __device__ __forceinline__ unsigned short cvt1(float f) {
  __bf16 b = (__bf16)f;
  return __builtin_bit_cast(unsigned short, b);
}
static __device__ __forceinline__ float bf2f(unsigned short h) {
  return __uint_as_float(((unsigned int)h) << 16);
}

// ---------------- prep ----------------
// Permuted col c in [0,512): cg=c>>6, gate=(c>>4)&3, cl=c&15;
// unit = cg*16 + cl; logical n = gate*128 + unit.
// wt_enc[c][k] = Whh_e[k][n]
// wt_dec[c][k] = Whh_d[k][n] + Wo[k][0]*wxd[n] + Wo[k][1]*wyd[n]  (pos fold)
// aux_enc[{0,1,2}*512+n] = wxe, wye, bbe ; aux_dec[n] = bbd (incl bo fold)
__global__ void prep_weights(const float* __restrict__ We,   const float* __restrict__ be,
                             const float* __restrict__ Wih_e,const float* __restrict__ Whh_e,
                             const float* __restrict__ b_e,
                             const float* __restrict__ Wd,   const float* __restrict__ bd,
                             const float* __restrict__ Wih_d,const float* __restrict__ Whh_d,
                             const float* __restrict__ b_d,
                             const float* __restrict__ Wo,   const float* __restrict__ bo,
                             unsigned short* __restrict__ wt_enc,
                             unsigned short* __restrict__ wt_dec,
                             float* __restrict__ aux_enc, float* __restrict__ aux_dec) {
  const int c = blockIdx.x & (NZ - 1);
  const bool dec = blockIdx.x >= NZ;
  const int cg = c >> 6, gate = (c >> 4) & 3, cl = c & 15;
  const int unit = cg * 16 + cl;
  const int n = gate * HID + unit;

  const float* Whh = dec ? Whh_d : Whh_e;
  const float* Wih = dec ? Wih_d : Wih_e;
  const float* Wem = dec ? Wd : We;
  const float* bem = dec ? bd : be;
  const float* bl  = dec ? b_d : b_e;
  unsigned short* wt = dec ? wt_dec : wt_enc;

  float wx = 0.f, wy = 0.f;
  for (int e = 0; e < HID; ++e) {
    wx += Wem[e] * Wih[e * NZ + n];
    wy += Wem[HID + e] * Wih[e * NZ + n];
  }
  for (int k = threadIdx.x; k < KWT; k += 64) {
    float v = Whh[k * NZ + n];
    if (dec) v += Wo[k * 2] * wx + Wo[k * 2 + 1] * wy;
    wt[c * KWT + k] = cvt1(v);
  }
  if (threadIdx.x == 0) {
    float bb = bl[n];
    for (int e = 0; e < HID; ++e) bb += bem[e] * Wih[e * NZ + n];
    if (!dec) {
      aux_enc[n] = wx; aux_enc[NZ + n] = wy; aux_enc[2 * NZ + n] = bb;
    } else {
      aux_dec[n] = bb + bo[0] * wx + bo[1] * wy;
    }
  }
}

// ---------------- main fused kernel ----------------
// MFMA 16x16x32 bf16 layouts (HW-verified r1-r4):
//  A/B frag: row/col = lane&15, k = 32kc + (lane>>4)*8 + j
//  C/D: col = lane&15, row = (lane>>4)*4 + reg
// h LDS swizzle: short-idx(r,k) = r*128 + (((k>>3) ^ (r&7))<<3) + (k&7)

#define AIDX(RROW, KC) \
  ((RROW) * 128 + (((((KC) * 4) + l4) ^ ((RROW) & 7)) << 3))

#define EXP4(D, S)                                                             \
  { f32x4 _s = (S);                                                            \
    D[0] = __builtin_amdgcn_exp2f(_s[0]); D[1] = __builtin_amdgcn_exp2f(_s[1]);\
    D[2] = __builtin_amdgcn_exp2f(_s[2]); D[3] = __builtin_amdgcn_exp2f(_s[3]); }
#define RCP4(D, S)                                                             \
  { f32x4 _r = (S);                                                            \
    D[0] = __builtin_amdgcn_rcpf(_r[0]); D[1] = __builtin_amdgcn_rcpf(_r[1]);  \
    D[2] = __builtin_amdgcn_rcpf(_r[2]); D[3] = __builtin_amdgcn_rcpf(_r[3]); }

#define LDB(DST, WB, KC)                                                       \
  { _Pragma("unroll")                                                          \
    for (int nt = 0; nt < 4; ++nt)                                             \
      DST[nt] = *(const u16x8*)((WB) + nt * 16 * KWT + (KC) * 32); }

#define INIT_ACC()                                                             \
  { _Pragma("unroll")                                                          \
    for (int m = 0; m < 2; ++m) {                                              \
      _Pragma("unroll")                                                        \
      for (int g = 0; g < 4; ++g)                                              \
        acc[m][g] = (f32x4){bb[g], bb[g], bb[g], bb[g]};                       \
    } }

#define MFMA_KC(KC, BF, CBUF)                                                  \
  { u16x8 _a0 = *(const u16x8*)&Als[CBUF][AIDX(rbase + l15, KC)];              \
    u16x8 _a1 = *(const u16x8*)&Als[CBUF][AIDX(rbase + 16 + l15, KC)];         \
    _Pragma("unroll")                                                          \
    for (int g = 0; g < 4; ++g) {                                              \
      acc[0][g] = __builtin_amdgcn_mfma_f32_16x16x32_bf16(                     \
          __builtin_bit_cast(bf16x8, _a0), __builtin_bit_cast(bf16x8, (BF)[g]),\
          acc[0][g], 0, 0, 0);                                                 \
      acc[1][g] = __builtin_amdgcn_mfma_f32_16x16x32_bf16(                     \
          __builtin_bit_cast(bf16x8, _a1), __builtin_bit_cast(bf16x8, (BF)[g]),\
          acc[1][g], 0, 0, 0);                                                 \
    } }

#define STEP_MM(WB, CBUF)                                                      \
  { u16x8 bA[4], bB[4];                                                        \
    LDB(bA, WB, 0) LDB(bB, WB, 1)                                              \
    INIT_ACC()                                                                 \
    MFMA_KC(0, bA, CBUF)                                                       \
    LDB(bA, WB, 2)                                                             \
    MFMA_KC(1, bB, CBUF)                                                       \
    LDB(bB, WB, 3)                                                             \
    MFMA_KC(2, bA, CBUF)                                                       \
    MFMA_KC(3, bB, CBUF) }

// gate math for m-tile M; FOLD literal 0/1; writes h into Als[NBUF]
#define GATE_M(M, FOLD, NBUF, PX, PY)                                          \
  { f32x4 zi = acc[M][0], zf = acc[M][1], zg = acc[M][2], zo = acc[M][3];      \
    if (FOLD) {                                                                \
      zi += PX * wx[0] + PY * wy[0];                                           \
      zf += PX * wx[1] + PY * wy[1];                                           \
      zg += PX * wx[2] + PY * wy[2];                                           \
      zo += PX * wx[3] + PY * wy[3];                                           \
    }                                                                          \
    f32x4 eB, eA, eG, eO;                                                      \
    EXP4(eB, zi * (-K2F)) EXP4(eA, zf * (-K2F))                                \
    EXP4(eG, zg * (-2.f * K2F)) EXP4(eO, zo * (-K2F))                          \
    f32x4 a1 = 1.f + eA, b1 = 1.f + eB, g1 = 1.f + eG;                         \
    f32x4 bg = b1 * g1;                                                        \
    f32x4 rd; RCP4(rd, a1 * bg)                                                \
    f32x4 cv = (crr[M] * bg + (1.f - eG) * a1) * rd;                           \
    crr[M] = cv;                                                               \
    f32x4 eC; EXP4(eC, cv * (-2.f * K2F))                                      \
    f32x4 rh; RCP4(rh, (1.f + eO) * (1.f + eC))                                \
    f32x4 hv = (1.f - eC) * rh;                                                \
    const int _R0 = rbase + (M) * 16 + l4 * 4;                                 \
    _Pragma("unroll")                                                          \
    for (int r = 0; r < 4; ++r)                                                \
      Als[NBUF][(_R0 + r) * 128 + ((uh ^ ((_R0 + r) & 7)) << 3) + ul] =        \
          cvt1(hv[r]);                                                         \
  }

// pos = h @ Wo + bo, fire-and-forget. 16 threads/row; Wo from L1.
// NOTE: all locals prefixed pp_ to avoid capturing macro args (r5 bug).
#define POS_PHASE(S, HB)                                                       \
  { const int pp_r = tid >> 4, pp_q = tid & 15;                                \
    u16x8 pp_h =                                                               \
        *(const u16x8*)&Als[HB][pp_r * 128 + ((pp_q ^ (pp_r & 7)) << 3)];      \
    const float* pp_w = Wo + pp_q * 16;                                        \
    f32x4 pp_w0 = *(const f32x4*)pp_w;                                         \
    f32x4 pp_w1 = *(const f32x4*)(pp_w + 4);                                   \
    f32x4 pp_w2 = *(const f32x4*)(pp_w + 8);                                   \
    f32x4 pp_w3 = *(const f32x4*)(pp_w + 12);                                  \
    f32x2 pp_s = (f32x2){0.f, 0.f};                                            \
    pp_s += bf2f(pp_h[0]) * (f32x2){pp_w0[0], pp_w0[1]};                       \
    pp_s += bf2f(pp_h[1]) * (f32x2){pp_w0[2], pp_w0[3]};                       \
    pp_s += bf2f(pp_h[2]) * (f32x2){pp_w1[0], pp_w1[1]};                       \
    pp_s += bf2f(pp_h[3]) * (f32x2){pp_w1[2], pp_w1[3]};                       \
    pp_s += bf2f(pp_h[4]) * (f32x2){pp_w2[0], pp_w2[1]};                       \
    pp_s += bf2f(pp_h[5]) * (f32x2){pp_w2[2], pp_w2[3]};                       \
    pp_s += bf2f(pp_h[6]) * (f32x2){pp_w3[0], pp_w3[1]};                       \
    pp_s += bf2f(pp_h[7]) * (f32x2){pp_w3[2], pp_w3[3]};                       \
    pp_s[0] += __shfl_xor(pp_s[0], 1); pp_s[1] += __shfl_xor(pp_s[1], 1);      \
    pp_s[0] += __shfl_xor(pp_s[0], 2); pp_s[1] += __shfl_xor(pp_s[1], 2);      \
    pp_s[0] += __shfl_xor(pp_s[0], 4); pp_s[1] += __shfl_xor(pp_s[1], 4);      \
    pp_s[0] += __shfl_xor(pp_s[0], 8); pp_s[1] += __shfl_xor(pp_s[1], 8);      \
    if (pp_q == 0) {                                                           \
      float2 pp_o; pp_o.x = pp_s[0] + bo0; pp_o.y = pp_s[1] + bo1;             \
      ((float2*)out)[(size_t)(S)*BATCH + row0 + pp_r] = pp_o;                  \
    } }

#define LOAD_PXPY(T)                                                           \
  { const float* obt =                                                         \
        obs + 2 * ((size_t)(T)*BATCH + row0 + rbase + l4 * 4);                 \
    f32x4 pa0 = *(const f32x4*)obt;                                            \
    f32x4 pa1 = *(const f32x4*)(obt + 4);                                      \
    f32x4 pb0 = *(const f32x4*)(obt + 32);                                     \
    f32x4 pb1 = *(const f32x4*)(obt + 36);                                     \
    px0 = (f32x4){pa0[0], pa0[2], pa1[0], pa1[2]};                             \
    py0 = (f32x4){pa0[1], pa0[3], pa1[1], pa1[3]};                             \
    px1 = (f32x4){pb0[0], pb0[2], pb1[0], pb1[2]};                             \
    py1 = (f32x4){pb0[1], pb0[3], pb1[1], pb1[3]}; }

__global__ __launch_bounds__(1024, 1) void lstm_fused(
    const float* __restrict__ obs,
    const unsigned short* __restrict__ wt_enc,
    const unsigned short* __restrict__ wt_dec,
    const float* __restrict__ aux_enc, const float* __restrict__ aux_dec,
    const float* __restrict__ Wo, const float* __restrict__ bo,
    float* __restrict__ out) {
  __shared__ unsigned short Als[2][ROWS * 128];   // 32 KB, XOR-swizzled

  const int tid = threadIdx.x;
  const int lane = tid & 63;
  const int wn = tid >> 6;          // 0..15
  const int l15 = lane & 15;
  const int l4 = lane >> 4;
  const int rg = wn >> 3, cg = wn & 7;
  const int rbase = rg * 32;
  const int row0 = blockIdx.x * ROWS;
  const int u = cg * 16 + l15;      // this lane's hidden unit
  const int uh = u >> 3, ul = u & 7;

  const float bo0 = bo[0], bo1 = bo[1];

  // per-lane loop-invariant B-frag base (nt/kc offsets are compile consts)
  const unsigned short* wB_e = wt_enc + (cg * 64 + l15) * KWT + l4 * 8;
  const unsigned short* wB_d = wt_dec + (cg * 64 + l15) * KWT + l4 * 8;

  // per-lane aux: 4 gates of unit u
  float wx[4], wy[4], bb[4];
#pragma unroll
  for (int g = 0; g < 4; ++g) {
    wx[g] = aux_enc[g * HID + u];
    wy[g] = aux_enc[NZ + g * HID + u];
    bb[g] = aux_enc[2 * NZ + g * HID + u];
  }

  f32x4 acc[2][4];    // [m-tile][gate]
  f32x4 crr[2];       // c state, f32 forever
  crr[0] = (f32x4){0.f, 0.f, 0.f, 0.f};
  crr[1] = (f32x4){0.f, 0.f, 0.f, 0.f};
  f32x4 px0, py0, px1, py1;

  int c = 0;
  // ---- encoder t=0: h=0 -> no matmul, z = bias + obs fold ----
  LOAD_PXPY(0)
  INIT_ACC()
  GATE_M(0, 1, c ^ 1, px0, py0)
  GATE_M(1, 1, c ^ 1, px1, py1)
  __syncthreads();
  c ^= 1;

  // ---- encoder t=1..7: 1 barrier/step ----
#pragma unroll 1
  for (int t = 1; t < OBS_LEN; ++t) {
    LOAD_PXPY(t)
    STEP_MM(wB_e, c)
    GATE_M(0, 1, c ^ 1, px0, py0)
    GATE_M(1, 1, c ^ 1, px1, py1)
    __syncthreads();
    c ^= 1;
  }

  // ---- enc -> dec transition (pos path folded into wt_dec) ----
#pragma unroll
  for (int g = 0; g < 4; ++g) bb[g] = aux_dec[g * HID + u];
  crr[0] = (f32x4){0.f, 0.f, 0.f, 0.f};
  crr[1] = (f32x4){0.f, 0.f, 0.f, 0.f};

  // ---- decoder: 1 barrier/step; POS(s-1) overlaps in MFMA shadow ----
#pragma unroll 1
  for (int s = 1; s < PRED_LEN; ++s) {
    STEP_MM(wB_d, c)
    POS_PHASE(s - 1, c)
    GATE_M(0, 0, c ^ 1, px0, py0)
    GATE_M(1, 0, c ^ 1, px1, py1)
    __syncthreads();
    c ^= 1;
  }
  POS_PHASE(PRED_LEN - 1, c)
}

extern "C" void kernel_launch(void* const* d_in, const int* in_sizes, int n_in,
                              void* d_out, int out_size, void* d_ws, size_t ws_size,
                              hipStream_t stream) {
  const float* obs   = (const float*)d_in[0];
  const float* We    = (const float*)d_in[1];
  const float* be    = (const float*)d_in[2];
  const float* Wih_e = (const float*)d_in[3];
  const float* Whh_e = (const float*)d_in[4];
  const float* b_e   = (const float*)d_in[5];
  const float* Wd    = (const float*)d_in[6];
  const float* bd    = (const float*)d_in[7];
  const float* Wih_d = (const float*)d_in[8];
  const float* Whh_d = (const float*)d_in[9];
  const float* b_d   = (const float*)d_in[10];
  const float* Wo    = (const float*)d_in[11];
  const float* bo    = (const float*)d_in[12];
  float* out = (float*)d_out;

  unsigned short* wt_enc = (unsigned short*)d_ws;                 // 128 KB
  unsigned short* wt_dec = wt_enc + NZ * KWT;                     // +128 KB
  float* aux_enc = (float*)(wt_dec + NZ * KWT);                   // 6 KB
  float* aux_dec = aux_enc + 3 * NZ;                              // 2 KB

  hipLaunchKernelGGL(prep_weights, dim3(2 * NZ), dim3(64), 0, stream,
                     We, be, Wih_e, Whh_e, b_e, Wd, bd, Wih_d, Whh_d, b_d,
                     Wo, bo, wt_enc, wt_dec, aux_enc, aux_dec);
  hipLaunchKernelGGL(lstm_fused, dim3(BATCH / ROWS), dim3(1024), 0, stream,
                     obs, wt_enc, wt_dec, aux_enc, aux_dec, Wo, bo, out);
}

// Round 7
// 529.063 us; speedup vs baseline: 4.1985x; 4.1985x over previous
//
#include <hip/hip_runtime.h>

// Round 7: 512 thr (8 waves, 2/SIMD, 256-reg budget -> no spills), 64 batch
// rows/block as TWO interleaved 32-row chunks. Per phase: chunk X's MFMA
// overlaps chunk Y's gate VALU inside the same wave stream; 1 barrier/phase,
// 2 phases/superstep. B-weights (gate-permuted Whh^T bf16) persistent in 64
// VGPRs -> zero per-step weight traffic. h single-buffered per chunk in LDS
// (XOR-swizzled, all write->read pairs barrier-separated). c in f32 regs.
// Decoder pos-path folded into Whh_d -> pure LSTM, POS fire-and-forget.

#define OBS_LEN 8
#define PRED_LEN 12
#define BATCH 131072
#define HID 128
#define NZ 512
#define KWT 128
#define CROWS 32      // rows per chunk
#define ROWSB 64      // rows per block

typedef float f32x4 __attribute__((ext_vector_type(4)));
typedef float f32x2 __attribute__((ext_vector_type(2)));
typedef unsigned short u16x8 __attribute__((ext_vector_type(8)));
typedef __bf16 bf16x8 __attribute__((ext_vector_type(8)));

#define K2F 1.4426950408889634f   // log2(e)

static __device__ __forceinline__ unsigned short cvt1(float f) {
  __bf16 b = (__bf16)f;
  return __builtin_bit_cast(unsigned short, b);
}
static __device__ __forceinline__ float bf2f(unsigned short h) {
  return __uint_as_float(((unsigned int)h) << 16);
}

// ---------------- prep (unchanged from r5/r6, HW-verified) ----------------
// Permuted col c in [0,512): cg=c>>6, gate=(c>>4)&3, cl=c&15;
// unit = cg*16 + cl; logical n = gate*128 + unit.
__global__ void prep_weights(const float* __restrict__ We,   const float* __restrict__ be,
                             const float* __restrict__ Wih_e,const float* __restrict__ Whh_e,
                             const float* __restrict__ b_e,
                             const float* __restrict__ Wd,   const float* __restrict__ bd,
                             const float* __restrict__ Wih_d,const float* __restrict__ Whh_d,
                             const float* __restrict__ b_d,
                             const float* __restrict__ Wo,   const float* __restrict__ bo,
                             unsigned short* __restrict__ wt_enc,
                             unsigned short* __restrict__ wt_dec,
                             float* __restrict__ aux_enc, float* __restrict__ aux_dec) {
  const int c = blockIdx.x & (NZ - 1);
  const bool dec = blockIdx.x >= NZ;
  const int cg = c >> 6, gate = (c >> 4) & 3, cl = c & 15;
  const int unit = cg * 16 + cl;
  const int n = gate * HID + unit;

  const float* Whh = dec ? Whh_d : Whh_e;
  const float* Wih = dec ? Wih_d : Wih_e;
  const float* Wem = dec ? Wd : We;
  const float* bem = dec ? bd : be;
  const float* bl  = dec ? b_d : b_e;
  unsigned short* wt = dec ? wt_dec : wt_enc;

  float wx = 0.f, wy = 0.f;
  for (int e = 0; e < HID; ++e) {
    wx += Wem[e] * Wih[e * NZ + n];
    wy += Wem[HID + e] * Wih[e * NZ + n];
  }
  for (int k = threadIdx.x; k < KWT; k += 64) {
    float v = Whh[k * NZ + n];
    if (dec) v += Wo[k * 2] * wx + Wo[k * 2 + 1] * wy;
    wt[c * KWT + k] = cvt1(v);
  }
  if (threadIdx.x == 0) {
    float bb = bl[n];
    for (int e = 0; e < HID; ++e) bb += bem[e] * Wih[e * NZ + n];
    if (!dec) {
      aux_enc[n] = wx; aux_enc[NZ + n] = wy; aux_enc[2 * NZ + n] = bb;
    } else {
      aux_dec[n] = bb + bo[0] * wx + bo[1] * wy;
    }
  }
}

// ---------------- main fused kernel ----------------
// MFMA 16x16x32 bf16 (HW-verified r1-r6):
//  A/B frag: row/col = lane&15, k = 32kc + (lane>>4)*8 + j
//  C/D: col = lane&15, row = (lane>>4)*4 + reg
// h LDS swizzle (verified r6): idx(r,k) = r*128 + (((k>>3)^(r&7))<<3) + (k&7)

#define EXP4(D, S)                                                             \
  { f32x4 _s = (S);                                                            \
    D[0] = __builtin_amdgcn_exp2f(_s[0]); D[1] = __builtin_amdgcn_exp2f(_s[1]);\
    D[2] = __builtin_amdgcn_exp2f(_s[2]); D[3] = __builtin_amdgcn_exp2f(_s[3]); }
#define RCP4(D, S)                                                             \
  { f32x4 _r = (S);                                                            \
    D[0] = __builtin_amdgcn_rcpf(_r[0]); D[1] = __builtin_amdgcn_rcpf(_r[1]);  \
    D[2] = __builtin_amdgcn_rcpf(_r[2]); D[3] = __builtin_amdgcn_rcpf(_r[3]); }

#define LOADW(WB)                                                              \
  { _Pragma("unroll")                                                          \
    for (int kc = 0; kc < 4; ++kc) {                                           \
      _Pragma("unroll")                                                        \
      for (int nt = 0; nt < 4; ++nt)                                           \
        bfr[kc][nt] = *(const u16x8*)((WB) + nt * 16 * KWT + kc * 32);         \
    } }

#define INITC(ACC, BB)                                                         \
  { _Pragma("unroll")                                                          \
    for (int m = 0; m < 2; ++m) {                                              \
      _Pragma("unroll")                                                        \
      for (int g = 0; g < 4; ++g)                                              \
        ACC[m][g] = (f32x4){(BB)[g], (BB)[g], (BB)[g], (BB)[g]};               \
    } }

// full K=128 matmul for one chunk: 8 ds_read_b128 + 32 MFMA
#define MMSTEP(ACC, HB, BB)                                                    \
  { INITC(ACC, BB)                                                             \
    _Pragma("unroll")                                                          \
    for (int kc = 0; kc < 4; ++kc) {                                           \
      const int _g = (((kc * 4 + l4) ^ (l15 & 7)) << 3);                       \
      u16x8 _a0 = *(const u16x8*)&hL[HB][l15 * 128 + _g];                      \
      u16x8 _a1 = *(const u16x8*)&hL[HB][(16 + l15) * 128 + _g];               \
      _Pragma("unroll")                                                        \
      for (int g = 0; g < 4; ++g) {                                            \
        ACC[0][g] = __builtin_amdgcn_mfma_f32_16x16x32_bf16(                   \
            __builtin_bit_cast(bf16x8, _a0),                                   \
            __builtin_bit_cast(bf16x8, bfr[kc][g]), ACC[0][g], 0, 0, 0);       \
        ACC[1][g] = __builtin_amdgcn_mfma_f32_16x16x32_bf16(                   \
            __builtin_bit_cast(bf16x8, _a1),                                   \
            __builtin_bit_cast(bf16x8, bfr[kc][g]), ACC[1][g], 0, 0, 0);       \
      } } }

// gate phase for one chunk (8 h/lane); FOLD literal 0/1 (enc adds obs embed)
#define GATEC(ACC, CRR, HB, FOLD)                                              \
  { _Pragma("unroll")                                                          \
    for (int m = 0; m < 2; ++m) {                                              \
      f32x4 g_zi = ACC[m][0], g_zf = ACC[m][1];                                \
      f32x4 g_zg = ACC[m][2], g_zo = ACC[m][3];                                \
      if (FOLD) {                                                              \
        f32x4 g_px = m ? px1 : px0, g_py = m ? py1 : py0;                      \
        g_zi += g_px * wx[0] + g_py * wy[0];                                   \
        g_zf += g_px * wx[1] + g_py * wy[1];                                   \
        g_zg += g_px * wx[2] + g_py * wy[2];                                   \
        g_zo += g_px * wx[3] + g_py * wy[3];                                   \
      }                                                                        \
      f32x4 g_eB, g_eA, g_eG, g_eO;                                            \
      EXP4(g_eB, g_zi * (-K2F)) EXP4(g_eA, g_zf * (-K2F))                      \
      EXP4(g_eG, g_zg * (-2.f * K2F)) EXP4(g_eO, g_zo * (-K2F))                \
      f32x4 g_a1 = 1.f + g_eA, g_b1 = 1.f + g_eB, g_g1 = 1.f + g_eG;           \
      f32x4 g_bg = g_b1 * g_g1;                                                \
      f32x4 g_rd; RCP4(g_rd, g_a1 * g_bg)                                      \
      f32x4 g_cv = (CRR[m] * g_bg + (1.f - g_eG) * g_a1) * g_rd;               \
      CRR[m] = g_cv;                                                           \
      f32x4 g_eC; EXP4(g_eC, g_cv * (-2.f * K2F))                              \
      f32x4 g_rh; RCP4(g_rh, (1.f + g_eO) * (1.f + g_eC))                      \
      f32x4 g_hv = (1.f - g_eC) * g_rh;                                        \
      const int g_R0 = 16 * m + l4 * 4;                                        \
      _Pragma("unroll")                                                        \
      for (int r = 0; r < 4; ++r)                                              \
        hL[HB][(g_R0 + r) * 128 + ((uh ^ ((g_R0 + r) & 7)) << 3) + ul] =       \
            cvt1(g_hv[r]);                                                     \
    } }

// pos = h @ Wo + bo, fire-and-forget. 16 thr/row over 32 rows.
#define POSC(S, HB, CO)                                                        \
  { const int pp_r = tid >> 4, pp_q = tid & 15;                                \
    u16x8 pp_h =                                                               \
        *(const u16x8*)&hL[HB][pp_r * 128 + ((pp_q ^ (pp_r & 7)) << 3)];       \
    const float* pp_w = Wo + pp_q * 16;                                        \
    f32x4 pp_w0 = *(const f32x4*)pp_w;                                         \
    f32x4 pp_w1 = *(const f32x4*)(pp_w + 4);                                   \
    f32x4 pp_w2 = *(const f32x4*)(pp_w + 8);                                   \
    f32x4 pp_w3 = *(const f32x4*)(pp_w + 12);                                  \
    f32x2 pp_s = (f32x2){0.f, 0.f};                                            \
    pp_s += bf2f(pp_h[0]) * (f32x2){pp_w0[0], pp_w0[1]};                       \
    pp_s += bf2f(pp_h[1]) * (f32x2){pp_w0[2], pp_w0[3]};                       \
    pp_s += bf2f(pp_h[2]) * (f32x2){pp_w1[0], pp_w1[1]};                       \
    pp_s += bf2f(pp_h[3]) * (f32x2){pp_w1[2], pp_w1[3]};                       \
    pp_s += bf2f(pp_h[4]) * (f32x2){pp_w2[0], pp_w2[1]};                       \
    pp_s += bf2f(pp_h[5]) * (f32x2){pp_w2[2], pp_w2[3]};                       \
    pp_s += bf2f(pp_h[6]) * (f32x2){pp_w3[0], pp_w3[1]};                       \
    pp_s += bf2f(pp_h[7]) * (f32x2){pp_w3[2], pp_w3[3]};                       \
    pp_s[0] += __shfl_xor(pp_s[0], 1); pp_s[1] += __shfl_xor(pp_s[1], 1);      \
    pp_s[0] += __shfl_xor(pp_s[0], 2); pp_s[1] += __shfl_xor(pp_s[1], 2);      \
    pp_s[0] += __shfl_xor(pp_s[0], 4); pp_s[1] += __shfl_xor(pp_s[1], 4);      \
    pp_s[0] += __shfl_xor(pp_s[0], 8); pp_s[1] += __shfl_xor(pp_s[1], 8);      \
    if (pp_q == 0) {                                                           \
      float2 pp_o; pp_o.x = pp_s[0] + bo0; pp_o.y = pp_s[1] + bo1;             \
      ((float2*)out)[(size_t)(S)*BATCH + row0 + (CO) + pp_r] = pp_o;           \
    } }

// load obs rows for one chunk's gate fold (px/py per m-tile)
#define LOADP(T, CO)                                                           \
  { const float* lp_b =                                                        \
        obs + 2 * ((size_t)(T)*BATCH + row0 + (CO) + l4 * 4);                  \
    f32x4 lp_q0 = *(const f32x4*)lp_b;                                         \
    f32x4 lp_q1 = *(const f32x4*)(lp_b + 4);                                   \
    f32x4 lp_q2 = *(const f32x4*)(lp_b + 32);                                  \
    f32x4 lp_q3 = *(const f32x4*)(lp_b + 36);                                  \
    px0 = (f32x4){lp_q0[0], lp_q0[2], lp_q1[0], lp_q1[2]};                     \
    py0 = (f32x4){lp_q0[1], lp_q0[3], lp_q1[1], lp_q1[3]};                     \
    px1 = (f32x4){lp_q2[0], lp_q2[2], lp_q3[0], lp_q3[2]};                     \
    py1 = (f32x4){lp_q2[1], lp_q2[3], lp_q3[1], lp_q3[3]}; }

__global__ __launch_bounds__(512, 2) void lstm_fused(
    const float* __restrict__ obs,
    const unsigned short* __restrict__ wt_enc,
    const unsigned short* __restrict__ wt_dec,
    const float* __restrict__ aux_enc, const float* __restrict__ aux_dec,
    const float* __restrict__ Wo, const float* __restrict__ bo,
    float* __restrict__ out) {
  __shared__ unsigned short hL[2][CROWS * 128];   // chunk A=0, B=1; 16 KB

  const int tid = threadIdx.x;
  const int lane = tid & 63;
  const int cg = tid >> 6;          // wave 0..7 -> units [16cg,16cg+16)
  const int l15 = lane & 15;
  const int l4 = lane >> 4;
  const int row0 = blockIdx.x * ROWSB;
  const int u = cg * 16 + l15;      // this lane's hidden unit
  const int uh = u >> 3, ul = u & 7;

  const float bo0 = bo[0], bo1 = bo[1];

  const unsigned short* wBe = wt_enc + (cg * 64 + l15) * KWT + l4 * 8;
  const unsigned short* wBd = wt_dec + (cg * 64 + l15) * KWT + l4 * 8;

  u16x8 bfr[4][4];                  // persistent B frags [kc][gate] = 64 regs
  LOADW(wBe);

  float wx[4], wy[4], bbE[4], bbD[4];
#pragma unroll
  for (int g = 0; g < 4; ++g) {
    wx[g]  = aux_enc[g * HID + u];
    wy[g]  = aux_enc[NZ + g * HID + u];
    bbE[g] = aux_enc[2 * NZ + g * HID + u];
  }

  f32x4 accA[2][4], accB[2][4];
  f32x4 crrA[2], crrB[2];
  crrA[0] = crrA[1] = (f32x4){0.f, 0.f, 0.f, 0.f};
  crrB[0] = crrB[1] = (f32x4){0.f, 0.f, 0.f, 0.f};
  f32x4 px0, py0, px1, py1;

  // ---- prologue: GATE_A(0) (h=0 -> z = bias + obs fold) ----
  LOADP(0, 0)
  INITC(accA, bbE)
  GATEC(accA, crrA, 0, 1)
  __syncthreads();

  // ---- alpha(1): MM_A(1) || GATE_B(0) ----
  LOADP(0, CROWS)
  MMSTEP(accA, 0, bbE)
  INITC(accB, bbE)
  GATEC(accB, crrB, 1, 1)
  __syncthreads();

  // ---- beta(1): MM_B(1) || GATE_A(1) ----
  LOADP(1, 0)
  MMSTEP(accB, 1, bbE)
  GATEC(accA, crrA, 0, 1)
  __syncthreads();

  // ---- encoder t=2..7 ----
#pragma unroll 1
  for (int t = 2; t < OBS_LEN; ++t) {
    LOADP(t - 1, CROWS)
    MMSTEP(accA, 0, bbE)
    GATEC(accB, crrB, 1, 1)
    __syncthreads();
    LOADP(t, 0)
    MMSTEP(accB, 1, bbE)
    GATEC(accA, crrA, 0, 1)
    __syncthreads();
  }

  // ---- enc -> dec transition ----
  LOADW(wBd);                      // enc MMs done; GATE_B(7) doesn't use bfr
#pragma unroll
  for (int g = 0; g < 4; ++g) bbD[g] = aux_dec[g * HID + u];
  crrA[0] = crrA[1] = (f32x4){0.f, 0.f, 0.f, 0.f};

  // alpha(d1): dec MM_A(1) || enc GATE_B(7) || POS0_A
  LOADP(OBS_LEN - 1, CROWS)
  MMSTEP(accA, 0, bbD)
  GATEC(accB, crrB, 1, 1)
  POSC(0, 0, 0)
  __syncthreads();
  crrB[0] = crrB[1] = (f32x4){0.f, 0.f, 0.f, 0.f};

  // beta(d1): dec MM_B(1) || dec GATE_A(1) || POS0_B
  MMSTEP(accB, 1, bbD)
  GATEC(accA, crrA, 0, 0)
  POSC(0, 1, CROWS)
  __syncthreads();

  // ---- decoder d=2..11 ----
#pragma unroll 1
  for (int d = 2; d < PRED_LEN; ++d) {
    MMSTEP(accA, 0, bbD)
    GATEC(accB, crrB, 1, 0)
    POSC(d - 1, 0, 0)
    __syncthreads();
    MMSTEP(accB, 1, bbD)
    GATEC(accA, crrA, 0, 0)
    POSC(d - 1, 1, CROWS)
    __syncthreads();
  }

  // ---- epilogue ----
  GATEC(accB, crrB, 1, 0)          // h_B(11)
  POSC(PRED_LEN - 1, 0, 0)         // pos11_A
  __syncthreads();
  POSC(PRED_LEN - 1, 1, CROWS)     // pos11_B
}

extern "C" void kernel_launch(void* const* d_in, const int* in_sizes, int n_in,
                              void* d_out, int out_size, void* d_ws, size_t ws_size,
                              hipStream_t stream) {
  const float* obs   = (const float*)d_in[0];
  const float* We    = (const float*)d_in[1];
  const float* be    = (const float*)d_in[2];
  const float* Wih_e = (const float*)d_in[3];
  const float* Whh_e = (const float*)d_in[4];
  const float* b_e   = (const float*)d_in[5];
  const float* Wd    = (const float*)d_in[6];
  const float* bd    = (const float*)d_in[7];
  const float* Wih_d = (const float*)d_in[8];
  const float* Whh_d = (const float*)d_in[9];
  const float* b_d   = (const float*)d_in[10];
  const float* Wo    = (const float*)d_in[11];
  const float* bo    = (const float*)d_in[12];
  float* out = (float*)d_out;

  unsigned short* wt_enc = (unsigned short*)d_ws;                 // 128 KB
  unsigned short* wt_dec = wt_enc + NZ * KWT;                     // +128 KB
  float* aux_enc = (float*)(wt_dec + NZ * KWT);                   // 6 KB
  float* aux_dec = aux_enc + 3 * NZ;                              // 2 KB

  hipLaunchKernelGGL(prep_weights, dim3(2 * NZ), dim3(64), 0, stream,
                     We, be, Wih_e, Whh_e, b_e, Wd, bd, Wih_d, Whh_d, b_d,
                     Wo, bo, wt_enc, wt_dec, aux_enc, aux_dec);
  hipLaunchKernelGGL(lstm_fused, dim3(BATCH / ROWSB), dim3(512), 0, stream,
                     obs, wt_enc, wt_dec, aux_enc, aux_dec, Wo, bo, out);
}